// Round 6
// baseline (145.622 us; speedup 1.0000x reference)
//
#include <hip/hip_runtime.h>
#include <hip/hip_bf16.h>
#include <math.h>

#define B_ 32
#define E_ 16384
#define N_ 1000
#define D_ 128
#define NN_ (N_ * N_)
#define T_ 4   // 128-edge sub-tiles per block; grid = B_*E_/(128*T_) = 1024

typedef __attribute__((ext_vector_type(8))) short bf16x8;
typedef __attribute__((ext_vector_type(4))) float f32x4;

// fp32 -> bf16 RNE (scalar; finite inputs)
__device__ __forceinline__ unsigned short f2bf(float f) {
    unsigned u = __float_as_uint(f);
    u += 0x7FFFu + ((u >> 16) & 1u);
    return (unsigned short)(u >> 16);
}

// packed pair fp32 -> bf16x2 (v_cvt_pk_bf16_f32)
__device__ __forceinline__ unsigned pk2(float lo, float hi) {
    __hip_bfloat162 h = __float22bfloat162_rn(make_float2(lo, hi));
    return *(unsigned*)&h;
}

__device__ __forceinline__ f32x4 mfma16(bf16x8 a, bf16x8 b, f32x4 c) {
    return __builtin_amdgcn_mfma_f32_16x16x32_bf16(a, b, c, 0, 0, 0);
}

__device__ __forceinline__ float silu_(float z) {
    return z * __builtin_amdgcn_rcpf(1.0f + __expf(-z));
}

// decode 17-bit quantized cell payload (call only when bit31 set; q >= 1)
__device__ __forceinline__ float dec17(unsigned x) {
    return (float)((x & 0x1FFFFu) - 1u) * (10.0f / 131070.0f);
}

// async global->LDS, 16B per lane (dest = wave-uniform base + lane*16)
__device__ __forceinline__ void gload_lds16(const void* g, void* l) {
    __builtin_amdgcn_global_load_lds(
        (const __attribute__((address_space(1))) unsigned*)g,
        (__attribute__((address_space(3))) unsigned*)l, 16, 0, 0);
}

// Pre-swizzle W1,W2 (128x128 fp32) -> bf16 at byte row*256 + ((col*2)^((row&7)<<4))
// so LINEAR global_load_lds reproduces the swizzled LDS image (rule 21).
__global__ void prep_weights(const float* __restrict__ W1,
                             const float* __restrict__ W2,
                             unsigned short* __restrict__ wsz) {
    int t = blockIdx.x * 256 + threadIdx.x;   // 0..32767
    int w = t >> 14, e = t & 16383;
    int row = e >> 7, col = e & 127;
    float v = (w ? W2 : W1)[e];
    char* dst = (char*)wsz + (size_t)w * 32768 + row * 256 + ((col * 2) ^ ((row & 7) << 4));
    *(unsigned short*)dst = f2bf(v);
}

__global__ __launch_bounds__(256, 2) void mlp_scatter_kernel(
    const float* __restrict__ X, const int* __restrict__ EI,
    const unsigned short* __restrict__ wsz,
    const float* __restrict__ b1, const float* __restrict__ b2,
    const float* __restrict__ Wo, const float* __restrict__ bo,
    unsigned* __restrict__ out)
{
    __shared__ __align__(16) char Wb[65536];   // W1 | W2 bf16, swizzled
    __shared__ __align__(16) char Hs[8192];    // 4 waves x [32 edges][32 f] bf16
    __shared__ __align__(16) float BiasL[384]; // b1 | b2 | Wo (fp32)

    const int tid = threadIdx.x;
    const int lane = tid & 63;
    const int wv = tid >> 6;
    const int l15 = lane & 15;
    const int g = (lane >> 4) & 3;
    char* hw = (char*)Hs + wv * 2048;

    const int bb = blockIdx.x >> 5;                 // batch (32 blocks per batch)
    const int e0 = (blockIdx.x & 31) * (128 * T_);  // edge base within batch

    // stage biases to LDS (keeps the main loop free of compiler vmem ops)
    if (tid < 96) {
        const float* src = tid < 32 ? b1 : (tid < 64 ? b2 : Wo);
        ((f32x4*)BiasL)[tid] = ((const f32x4*)src)[tid & 31];
    }
    const float bo0 = bo[0];

    // EI preload for all sub-tiles (prologue only; static indexing -> registers)
    int eis[T_][2], eid[T_][2];
    #pragma unroll
    for (int st = 0; st < T_; ++st)
        #pragma unroll
        for (int m = 0; m < 2; ++m) {
            int e = e0 + st * 128 + wv * 32 + m * 16 + l15;
            eis[st][m] = EI[(size_t)bb * 2 * E_ + e];
            eid[st][m] = EI[(size_t)bb * 2 * E_ + E_ + e];
        }

    // X prefetch registers: asm-pinned (not rematerializable). EARLY-CLOBBER
    // outputs ("=&v") so no output tuple can alias the address pair %8.
    f32x4 af[2][4][2];

#define ISSUE_M(stv, mm) do {                                                        \
        unsigned long long _ad = (unsigned long long)X +                             \
            (((unsigned long long)((size_t)bb * E_ + e0 + (stv) * 128 + wv * 32 +    \
                                   (mm) * 16 + l15)) << 9) + (unsigned)(g * 32);     \
        asm volatile(                                                                \
            "global_load_dwordx4 %0, %8, off\n\t"                                    \
            "global_load_dwordx4 %1, %8, off offset:16\n\t"                          \
            "global_load_dwordx4 %2, %8, off offset:128\n\t"                         \
            "global_load_dwordx4 %3, %8, off offset:144\n\t"                         \
            "global_load_dwordx4 %4, %8, off offset:256\n\t"                         \
            "global_load_dwordx4 %5, %8, off offset:272\n\t"                         \
            "global_load_dwordx4 %6, %8, off offset:384\n\t"                         \
            "global_load_dwordx4 %7, %8, off offset:400"                             \
            : "=&v"(af[mm][0][0]), "=&v"(af[mm][0][1]), "=&v"(af[mm][1][0]),         \
              "=&v"(af[mm][1][1]), "=&v"(af[mm][2][0]), "=&v"(af[mm][2][1]),         \
              "=&v"(af[mm][3][0]), "=&v"(af[mm][3][1])                               \
            : "v"(_ad));                                                             \
    } while (0)

    ISSUE_M(0, 0);
    ISSUE_M(0, 1);

    // stage both weight matrices: 64KB linear, zero VALU
    #pragma unroll
    for (int it = 0; it < 16; ++it) {
        int off = it * 4096 + tid * 16;
        gload_lds16((const char*)wsz + off, Wb + off);
    }
    asm volatile("s_waitcnt vmcnt(0)" ::: "memory");
    __builtin_amdgcn_sched_barrier(0);
    __syncthreads();   // the only barrier

    #pragma unroll
    for (int st = 0; st < T_; ++st) {
        // all but the newest 2 vmem ops (= prev sub-tile's atomics) complete,
        // i.e. this sub-tile's 16 X loads have landed.
        asm volatile("s_waitcnt vmcnt(2)" ::: "memory");
        __builtin_amdgcn_sched_barrier(0);

        // convert X tile to bf16 fragments (af regs die here)
        bf16x8 a[2][4];
        #pragma unroll
        for (int m = 0; m < 2; ++m)
            #pragma unroll
            for (int ks = 0; ks < 4; ++ks) {
                bf16x8 t;
                unsigned* tu = (unsigned*)&t;
                tu[0] = pk2(af[m][ks][0][0], af[m][ks][0][1]);
                tu[1] = pk2(af[m][ks][0][2], af[m][ks][0][3]);
                tu[2] = pk2(af[m][ks][1][0], af[m][ks][1][1]);
                tu[3] = pk2(af[m][ks][1][2], af[m][ks][1][3]);
                a[m][ks] = t;
            }

        // prefetch the ENTIRE next sub-tile NOW: the whole tile body's
        // MFMA+VALU (~1500+ cyc across resident waves) covers HBM latency.
        if (st + 1 < T_) { ISSUE_M(st + 1, 0); ISSUE_M(st + 1, 1); }

        f32x4 acc2[2][8];
        #pragma unroll
        for (int m = 0; m < 2; ++m)
            #pragma unroll
            for (int n = 0; n < 8; ++n)
                acc2[m][n] = (f32x4){0.f, 0.f, 0.f, 0.f};

        // quarter-feature pipeline: GEMM1 q -> H -> GEMM2 k-slice q
        #pragma unroll
        for (int q = 0; q < 4; ++q) {
            f32x4 acc1[2][2];
            #pragma unroll
            for (int m = 0; m < 2; ++m)
                #pragma unroll
                for (int nn = 0; nn < 2; ++nn)
                    acc1[m][nn] = (f32x4){0.f, 0.f, 0.f, 0.f};

            #pragma unroll
            for (int ks = 0; ks < 4; ++ks)
                #pragma unroll
                for (int nn = 0; nn < 2; ++nn) {
                    int row = l15 + (q * 2 + nn) * 16;
                    bf16x8 aw = *(const bf16x8*)(Wb + row * 256 +
                                  ((ks * 64 + g * 16) ^ ((row & 7) << 4)));
                    acc1[0][nn] = mfma16(aw, a[0][ks], acc1[0][nn]);
                    acc1[1][nn] = mfma16(aw, a[1][ks], acc1[1][nn]);
                }

            #pragma unroll
            for (int nn = 0; nn < 2; ++nn) {
                f32x4 b1q = ((f32x4*)BiasL)[(q * 2 + nn) * 4 + g];
                #pragma unroll
                for (int m = 0; m < 2; ++m) {
                    float h0 = silu_(acc1[m][nn][0] + b1q[0]);
                    float h1 = silu_(acc1[m][nn][1] + b1q[1]);
                    float h2 = silu_(acc1[m][nn][2] + b1q[2]);
                    float h3 = silu_(acc1[m][nn][3] + b1q[3]);
                    int edge = m * 16 + l15;
                    *(uint2*)(hw + edge * 64 + ((nn * 32 + g * 8) ^ ((edge & 6) << 3))) =
                        make_uint2(pk2(h0, h1), pk2(h2, h3));
                }
            }

            bf16x8 hb[2];
            #pragma unroll
            for (int m = 0; m < 2; ++m) {
                int edge = m * 16 + l15;
                hb[m] = *(const bf16x8*)(hw + edge * 64 + ((g * 16) ^ ((edge & 6) << 3)));
            }
            #pragma unroll
            for (int n = 0; n < 8; ++n) {
                int row = l15 + n * 16;
                bf16x8 w2 = *(const bf16x8*)(Wb + 32768 + row * 256 +
                              ((q * 64 + g * 16) ^ ((row & 7) << 4)));
                acc2[0][n] = mfma16(w2, hb[0], acc2[0][n]);
                acc2[1][n] = mfma16(w2, hb[1], acc2[1][n]);
            }
        }

        // epilogue: lane holds f2 = n*16+g*4+r for edge m*16+l15
        float zed[2] = {0.f, 0.f};
        #pragma unroll
        for (int n = 0; n < 8; ++n) {
            f32x4 b2q = ((f32x4*)BiasL)[32 + n * 4 + g];
            f32x4 woq = ((f32x4*)BiasL)[64 + n * 4 + g];
            #pragma unroll
            for (int m = 0; m < 2; ++m) {
                zed[m] += silu_(acc2[m][n][0] + b2q[0]) * woq[0];
                zed[m] += silu_(acc2[m][n][1] + b2q[1]) * woq[1];
                zed[m] += silu_(acc2[m][n][2] + b2q[2]) * woq[2];
                zed[m] += silu_(acc2[m][n][3] + b2q[3]) * woq[3];
            }
        }

        #pragma unroll
        for (int m = 0; m < 2; ++m) {
            zed[m] += __shfl_xor(zed[m], 16, 64);
            zed[m] += __shfl_xor(zed[m], 32, 64);
        }

        // sigmoid*10, pack bit31 | e<<17 | q17, atomicMax scatter (last-e-wins)
        if (g == 0) {
            #pragma unroll
            for (int m = 0; m < 2; ++m) {
                int e = e0 + st * 128 + wv * 32 + m * 16 + l15;
                float z = zed[m] + bo0;
                float val = 10.0f * __builtin_amdgcn_rcpf(1.0f + __expf(-z));
                unsigned qv = (unsigned)(val * 13107.0f + 0.5f) + 1u;  // 131070/10
                if (qv > 0x1FFFFu) qv = 0x1FFFFu;
                unsigned packed = 0x80000000u | ((unsigned)e << 17) | qv;
                unsigned long long aaddr = (unsigned long long)(out +
                    ((size_t)bb * NN_ + (size_t)eis[st][m] * N_ + eid[st][m]));
                asm volatile("global_atomic_umax %0, %1, off"
                             :: "v"(aaddr), "v"(packed) : "memory");
            }
        }
    }
#undef ISSUE_M
}

// Fused finalize. Cell states: 0 = empty (= final 0.0f); bit31 set = packed
// quantized edge value; bit31 clear & nonzero = already-final float in (0,10].
// The symmetrized value is identical for (s,d) and (d,s), and every writer of
// a cell writes the same v, so concurrent/stale reads are benign: a stale read
// just sees the packed form and recomputes the identical v.
__global__ __launch_bounds__(256) void finalize_fused(
    const int* __restrict__ EI, unsigned* __restrict__ out)
{
    int i = blockIdx.x * 256 + threadIdx.x;   // 0..B*E-1
    int b = i >> 14, e = i & 16383;
    int s = EI[(size_t)b * 2 * E_ + e];
    int d = EI[(size_t)b * 2 * E_ + E_ + e];
    unsigned* ob = out + (size_t)b * NN_;
    unsigned x1 = ob[(size_t)s * N_ + d];
    unsigned x2 = ob[(size_t)d * N_ + s];
    float v;
    if (!(x1 >> 31) && x1)      v = __uint_as_float(x1);   // already final
    else if (!(x2 >> 31) && x2) v = __uint_as_float(x2);   // already final
    else {
        float c1 = (x1 >> 31) ? dec17(x1) : 0.0f;
        float c2 = (x2 >> 31) ? dec17(x2) : 0.0f;
        v = 0.5f * (c1 + c2);
    }
    unsigned uv = __float_as_uint(v);
    ob[(size_t)s * N_ + d] = uv;
    ob[(size_t)d * N_ + s] = uv;
}

extern "C" void kernel_launch(void* const* d_in, const int* in_sizes, int n_in,
                              void* d_out, int out_size, void* d_ws, size_t ws_size,
                              hipStream_t stream) {
    const float* X  = (const float*)d_in[0];
    const int*   EI = (const int*)d_in[1];
    const float* W1 = (const float*)d_in[2];
    const float* b1 = (const float*)d_in[3];
    const float* W2 = (const float*)d_in[4];
    const float* b2 = (const float*)d_in[5];
    const float* Wo = (const float*)d_in[6];
    const float* bo = (const float*)d_in[7];
    unsigned* out = (unsigned*)d_out;
    unsigned short* wsz = (unsigned short*)d_ws;

    prep_weights<<<dim3(128), dim3(256), 0, stream>>>(W1, W2, wsz);
    hipMemsetAsync(d_out, 0, (size_t)B_ * NN_ * sizeof(float), stream);
    mlp_scatter_kernel<<<dim3((B_ * E_) / (128 * T_)), dim3(256), 0, stream>>>(
        X, EI, wsz, b1, b2, Wo, bo, out);
    finalize_fused<<<dim3((B_ * E_) / 256), dim3(256), 0, stream>>>(EI, out);
}